// Round 12
// baseline (151.441 us; speedup 1.0000x reference)
//
#include <hip/hip_runtime.h>
#include <cstdint>

#define N 4096
#define D 1024
#define KC_COUNT (D / 32)    // 32 k-chunks of 32
#define NP 4128              // N padded to a multiple of 96
#define TG (NP / 96)         // 43 tile rows/cols of 96
#define NBLK (TG * (TG + 1) / 2)   // 946 upper-triangular 96x96 tiles

typedef _Float16 f16;
typedef __attribute__((ext_vector_type(8))) _Float16 f16x8;
typedef __attribute__((ext_vector_type(4))) float f32x4;

// Monotone map fp32 -> u32 so unsigned compare == float compare (ascending).
__device__ __forceinline__ unsigned int orderable(float f) {
    unsigned int b = __float_as_uint(f);
    return (b & 0x80000000u) ? ~b : (b | 0x80000000u);
}

__device__ __forceinline__ void async_copy16(const f16* g, f16* l) {
    __builtin_amdgcn_global_load_lds(
        (const __attribute__((address_space(1))) uint32_t*)(const void*)g,
        (__attribute__((address_space(3))) uint32_t*)(void*)l,
        16 /*bytes*/, 0 /*offset*/, 0 /*aux*/);
}

// Direct fp32 -> f16 hi/lo split, written straight to MFMA fragment order
// (no LDS, no barriers). Validated round 11: -5.6 us vs LDS version.
__global__ __launch_bounds__(256) void split_direct(
    const float* __restrict__ X, f16* __restrict__ Xsw,
    unsigned long long* __restrict__ keys)
{
    const int tid = threadIdx.x;
    const int bid = blockIdx.x;
    const int rg = bid >> 2, kq = bid & 3;
    const int lane = tid & 63, w = tid >> 6;
    const int m = lane & 15, qq = lane >> 4;

    if (bid < 32) keys[bid * 256 + tid] = 0xFFFFFFFFFFFFFFFFull;

#pragma unroll
    for (int s = 0; s < 2; ++s) {
        const int kc = kq * 8 + w * 2 + s;   // 8 kc of this quarter over 4 waves
        f16x8 h = (f16x8)(f16)0, l = (f16x8)(f16)0;
        if (rg < 256) {
            const float* src = X + (size_t)(rg * 16 + m) * D + kc * 32 + qq * 8;
            const float4 v0 = *(const float4*)src;
            const float4 v1 = *(const float4*)(src + 4);
            const float xs[8] = {v0.x, v0.y, v0.z, v0.w, v1.x, v1.y, v1.z, v1.w};
#pragma unroll
            for (int e = 0; e < 8; ++e) {
                const f16 hh = (f16)xs[e];
                h[e] = hh;
                l[e] = (f16)(xs[e] - (float)hh);
            }
        }
        f16* dst = Xsw + ((size_t)(rg * KC_COUNT + kc) * 2) * 512 + lane * 8;
        *(f16x8*)dst = h;            // hl=0 plane
        *(f16x8*)(dst + 512) = l;    // hl=1 plane
    }
}

// 96x96 upper-triangular tile of dist = X @ X^T, 4 waves (2x2 of 48x48),
// f16-split MFMA (hi*hi + hi*lo + lo*hi), 2-barrier loop.
// THIS ROUND: A-operand is NOT LDS-staged -- Xsw is already in fragment
// order, so each wave global_load_dwordx4's its 6 A-fragments (hi/lo x 3
// rows) to registers per kc-step (coalesced 1 KB/inst; panel reuse across
// same-XCD blocks -> L2-hits, helped by T1 swizzle). Only B goes via LDS
// (12 chunks/step). LDS-port cost per block-step: 768 -> 384 cyc (writes
// 24->12 KB, ds_reads 48->24) -- the measured co-limiter (~38 us of 74).
// The A-loads drain at the existing __syncthreads vmcnt(0); no new sync.
__global__ __launch_bounds__(256, 4) void gemm_argmin_sym(
    const f16* __restrict__ Xsw, const int* __restrict__ labels,
    unsigned long long* __restrict__ keys_ap,
    unsigned long long* __restrict__ keys_an)
{
    __shared__ f16 Bs[6 * 2 * 512];   // 12 KB (B only)

    // T1 XCD-chunked bijective remap (kept: FETCH-neutral-or-better).
    const int b = blockIdx.x;
    const int xcd = b & 7;
    const int q = NBLK >> 3, rem = NBLK & 7;   // 118, 2
    const int wg = (xcd < rem ? xcd * (q + 1)
                              : rem * (q + 1) + (xcd - rem) * q) + (b >> 3);

    // Decode work id -> (ti, tj) with ti <= tj over TG=43.
    int r = wg, ti = 0;
    while (r >= TG - ti) { r -= TG - ti; ++ti; }
    const int tj = ti + r;

    const int tid = threadIdx.x;
    const int lane = tid & 63;
    const int w = tid >> 6;            // wave 0..3
    const int wr = w >> 1, wc = w & 1; // 2x2 wave grid, 48x48 region each
    const int rowBase = ti * 96, colBase = tj * 96;

    f32x4 acc[3][3];
#pragma unroll
    for (int mi = 0; mi < 3; ++mi)
#pragma unroll
        for (int ni = 0; ni < 3; ++ni) acc[mi][ni] = (f32x4){0.f, 0.f, 0.f, 0.f};

    // B staging: wave w stages chunks c = w*3 .. w*3+2 (12 total: 6rg x hi/lo).
    const f16* gB[3];
    f16* lpB[3];
#pragma unroll
    for (int j = 0; j < 3; ++j) {
        int c = w * 3 + j;
        int rgL = c >> 1, hl = c & 1;
        int rgG = tj * 6 + rgL;
        gB[j] = Xsw + ((((size_t)rgG * KC_COUNT) * 2 + hl) * 64 + lane) * 8;  // kc=0
        lpB[j] = Bs + (rgL * 2 + hl) * 512;  // wave-uniform base
    }

    // A direct-load pointers: wave reads rows rgA = ti*6 + wr*3 + t2, hi/lo.
    const f16* gA[3][2];
#pragma unroll
    for (int t2 = 0; t2 < 3; ++t2) {
        int rgG = ti * 6 + wr * 3 + t2;
#pragma unroll
        for (int hl = 0; hl < 2; ++hl)
            gA[t2][hl] = Xsw + ((((size_t)rgG * KC_COUNT) * 2 + hl) * 64 + lane) * 8;
    }

    for (int kc = 0; kc < KC_COUNT; ++kc) {
        const size_t ko = (size_t)kc * 1024;
#pragma unroll
        for (int j = 0; j < 3; ++j)
            async_copy16(gB[j] + ko, lpB[j]);

        f16x8 ah[3], al[3];
#pragma unroll
        for (int t2 = 0; t2 < 3; ++t2) {
            ah[t2] = *(const f16x8*)(gA[t2][0] + ko);
            al[t2] = *(const f16x8*)(gA[t2][1] + ko);
        }
        __syncthreads();   // drains vmcnt(0): B tile in LDS, A frags in regs

        f16x8 bh[3], bl[3];
#pragma unroll
        for (int t2 = 0; t2 < 3; ++t2) {
            int rgB = wc * 3 + t2;
            bh[t2] = *(const f16x8*)(Bs + (rgB * 2 + 0) * 512 + lane * 8);
            bl[t2] = *(const f16x8*)(Bs + (rgB * 2 + 1) * 512 + lane * 8);
        }
#pragma unroll
        for (int mi = 0; mi < 3; ++mi)
#pragma unroll
            for (int ni = 0; ni < 3; ++ni) {
                acc[mi][ni] = __builtin_amdgcn_mfma_f32_16x16x32_f16(
                    ah[mi], bh[ni], acc[mi][ni], 0, 0, 0);
                acc[mi][ni] = __builtin_amdgcn_mfma_f32_16x16x32_f16(
                    ah[mi], bl[ni], acc[mi][ni], 0, 0, 0);
                acc[mi][ni] = __builtin_amdgcn_mfma_f32_16x16x32_f16(
                    al[mi], bh[ni], acc[mi][ni], 0, 0, 0);
            }
        __syncthreads();   // all B reads done before next stage overwrites
    }

    // Epilogue. C/D layout (16x16): col = lane&15, row = (lane>>4)*4 + reg.
    const int g16 = lane >> 4, c16 = lane & 15;

    int ljv[3], liv[3][4];
#pragma unroll
    for (int ni = 0; ni < 3; ++ni) {
        const int j = colBase + wc * 48 + ni * 16 + c16;
        ljv[ni] = (j < N) ? labels[j] : -1;    // pad sentinel: matches nothing
    }
#pragma unroll
    for (int mi = 0; mi < 3; ++mi)
#pragma unroll
        for (int reg = 0; reg < 4; ++reg) {
            const int i = rowBase + wr * 48 + mi * 16 + g16 * 4 + reg;
            liv[mi][reg] = (i < N) ? labels[i] : -1;
        }

    // Pass 1: row-side argmin (rows of ti-range over cols of tj-range).
#pragma unroll
    for (int mi = 0; mi < 3; ++mi) {
#pragma unroll
        for (int reg = 0; reg < 4; ++reg) {
            const int i = rowBase + wr * 48 + mi * 16 + g16 * 4 + reg;
            const int li = liv[mi][reg];
            float bestAp = __builtin_huge_valf(); int jAp = 0;
            float bestAn = __builtin_huge_valf(); int jAn = 0;
#pragma unroll
            for (int ni = 0; ni < 3; ++ni) {
                const int jcol = colBase + wc * 48 + ni * 16 + c16;
                const float v = acc[mi][ni][reg];
                const bool same = (li == ljv[ni]);
                const float vap = (same && (i != jcol)) ? v : v + 2.0f;
                const float van = (!same) ? v : v + 2.0f;
                if (vap < bestAp) { bestAp = vap; jAp = jcol; }
                if (van < bestAn) { bestAn = van; jAn = jcol; }
            }
            unsigned long long kap =
                ((unsigned long long)orderable(bestAp) << 32) | (unsigned)jAp;
            unsigned long long kan =
                ((unsigned long long)orderable(bestAn) << 32) | (unsigned)jAn;
#pragma unroll
            for (int off = 1; off < 16; off <<= 1) {
                unsigned long long o = __shfl_xor(kap, off); kap = o < kap ? o : kap;
                o = __shfl_xor(kan, off); kan = o < kan ? o : kan;
            }
            if (c16 == 0 && i < N) {
                atomicMin(&keys_ap[i], kap);
                atomicMin(&keys_an[i], kan);
            }
        }
    }

    // Pass 2 (off-diagonal only): column-side argmin via symmetry.
    if (ti != tj) {
#pragma unroll
        for (int ni = 0; ni < 3; ++ni) {
            const int j = colBase + wc * 48 + ni * 16 + c16;
            const int lj = ljv[ni];
            float bestAp = __builtin_huge_valf(); int iAp = 0;
            float bestAn = __builtin_huge_valf(); int iAn = 0;
#pragma unroll
            for (int mi = 0; mi < 3; ++mi)
#pragma unroll
                for (int reg = 0; reg < 4; ++reg) {
                    const int i = rowBase + wr * 48 + mi * 16 + g16 * 4 + reg;
                    const float v = acc[mi][ni][reg];
                    // pad rows have label -1 != lj -> negative, v = 0: never wins
                    const bool same = (liv[mi][reg] == lj);
                    const float vap = same ? v : v + 2.0f;   // i != j off-diag
                    const float van = (!same) ? v : v + 2.0f;
                    if (vap < bestAp) { bestAp = vap; iAp = i; }
                    if (van < bestAn) { bestAn = van; iAn = i; }
                }
            unsigned long long kap =
                ((unsigned long long)orderable(bestAp) << 32) | (unsigned)iAp;
            unsigned long long kan =
                ((unsigned long long)orderable(bestAn) << 32) | (unsigned)iAn;
            // Reduce over g16 (lane bits 4,5): lanes sharing c16 share j.
#pragma unroll
            for (int off = 16; off < 64; off <<= 1) {
                unsigned long long o = __shfl_xor(kap, off); kap = o < kap ? o : kap;
                o = __shfl_xor(kan, off); kan = o < kan ? o : kan;
            }
            if (g16 == 0 && j < N) {
                atomicMin(&keys_ap[j], kap);
                atomicMin(&keys_an[j], kan);
            }
        }
    }
}

__global__ void gather_rows(const float* __restrict__ A,
                            const unsigned long long* __restrict__ keys_ap,
                            const unsigned long long* __restrict__ keys_an,
                            float* __restrict__ out)
{
    const int row = blockIdx.x;
    const int t = threadIdx.x;
    const int ja = (int)(keys_ap[row] & 0xFFFFFFFFull);
    const int jn = (int)(keys_an[row] & 0xFFFFFFFFull);
    const float4* Av = (const float4*)A;
    float4* Ov = (float4*)out;
    Ov[(size_t)row * (D / 4) + t]       = Av[(size_t)ja * (D / 4) + t];
    Ov[(size_t)(N + row) * (D / 4) + t] = Av[(size_t)jn * (D / 4) + t];
}

extern "C" void kernel_launch(void* const* d_in, const int* in_sizes, int n_in,
                              void* d_out, int out_size, void* d_ws, size_t ws_size,
                              hipStream_t stream) {
    const float* A = (const float*)d_in[0];
    const int* labels = (const int*)d_in[1];  // integer inputs arrive as int32
    float* out = (float*)d_out;

    unsigned long long* keys = (unsigned long long*)d_ws;          // 64 KB
    f16* Xsw = (f16*)((char*)d_ws + 65536);   // 258 rg * 64 KB = 16.9 MB hi+lo

    split_direct<<<258 * 4, 256, 0, stream>>>(A, Xsw, keys);
    gemm_argmin_sym<<<NBLK, 256, 0, stream>>>(Xsw, labels, keys, keys + N);
    gather_rows<<<N, 256, 0, stream>>>(A, keys, keys + N, out);
}

// Round 13
// 151.186 us; speedup vs baseline: 1.0017x; 1.0017x over previous
//
#include <hip/hip_runtime.h>
#include <cstdint>

#define N 4096
#define D 1024
#define KC_COUNT (D / 32)    // 32 k-chunks of 32
#define NP 4128              // N padded to a multiple of 96
#define TG (NP / 96)         // 43 tile rows/cols of 96
#define NBLK (TG * (TG + 1) / 2)   // 946 upper-triangular 96x96 tiles
#define BUFSZ (6 * 2 * 512)  // 6144 f16 = 12 KB per B buffer

typedef _Float16 f16;
typedef __attribute__((ext_vector_type(8))) _Float16 f16x8;
typedef __attribute__((ext_vector_type(4))) float f32x4;

// Monotone map fp32 -> u32 so unsigned compare == float compare (ascending).
__device__ __forceinline__ unsigned int orderable(float f) {
    unsigned int b = __float_as_uint(f);
    return (b & 0x80000000u) ? ~b : (b | 0x80000000u);
}

__device__ __forceinline__ void async_copy16(const f16* g, f16* l) {
    __builtin_amdgcn_global_load_lds(
        (const __attribute__((address_space(1))) uint32_t*)(const void*)g,
        (__attribute__((address_space(3))) uint32_t*)(void*)l,
        16 /*bytes*/, 0 /*offset*/, 0 /*aux*/);
}

// Direct fp32 -> f16 hi/lo split, written straight to MFMA fragment order
// (no LDS, no barriers). Validated round 11: -5.6 us vs LDS version.
__global__ __launch_bounds__(256) void split_direct(
    const float* __restrict__ X, f16* __restrict__ Xsw,
    unsigned long long* __restrict__ keys)
{
    const int tid = threadIdx.x;
    const int bid = blockIdx.x;
    const int rg = bid >> 2, kq = bid & 3;
    const int lane = tid & 63, w = tid >> 6;
    const int m = lane & 15, qq = lane >> 4;

    if (bid < 32) keys[bid * 256 + tid] = 0xFFFFFFFFFFFFFFFFull;

#pragma unroll
    for (int s = 0; s < 2; ++s) {
        const int kc = kq * 8 + w * 2 + s;   // 8 kc of this quarter over 4 waves
        f16x8 h = (f16x8)(f16)0, l = (f16x8)(f16)0;
        if (rg < 256) {
            const float* src = X + (size_t)(rg * 16 + m) * D + kc * 32 + qq * 8;
            const float4 v0 = *(const float4*)src;
            const float4 v1 = *(const float4*)(src + 4);
            const float xs[8] = {v0.x, v0.y, v0.z, v0.w, v1.x, v1.y, v1.z, v1.w};
#pragma unroll
            for (int e = 0; e < 8; ++e) {
                const f16 hh = (f16)xs[e];
                h[e] = hh;
                l[e] = (f16)(xs[e] - (float)hh);
            }
        }
        f16* dst = Xsw + ((size_t)(rg * KC_COUNT + kc) * 2) * 512 + lane * 8;
        *(f16x8*)dst = h;            // hl=0 plane
        *(f16x8*)(dst + 512) = l;    // hl=1 plane
    }
}

// 96x96 upper-triangular tile of dist = X @ X^T, 4 waves (2x2 of 48x48),
// f16-split MFMA (hi*hi + hi*lo + lo*hi).
// THIS ROUND: single-barrier ping-pong double-buffer for B (2 x 12 KB) +
// A direct-to-register global loads (round 12, neutral but halves LDS).
// Schedule per kc: loadA(kc) -> ONE __syncthreads -> stage(kc+1 -> buf^1)
// -> ds_read buf[cur] -> MFMA. The barrier's vmcnt(0) drains stage(kc)
// (issued a FULL compute phase earlier -> latency covered, unlike the
// 2-barrier loop where stage and drain are back-to-back with zero cover).
// Write-after-read safe: buf^1's readers (kc-1) finished ds_reads before
// their mfma, hence before this barrier; stage issues after it.
// Measured plateau so far: 2-barrier 73-74, counted-vmcnt 77, 128^2 92.
__global__ __launch_bounds__(256, 4) void gemm_argmin_sym(
    const f16* __restrict__ Xsw, const int* __restrict__ labels,
    unsigned long long* __restrict__ keys_ap,
    unsigned long long* __restrict__ keys_an)
{
    __shared__ f16 Bs[2][BUFSZ];   // 24 KB ping-pong (B only)

    // T1 XCD-chunked bijective remap (kept: FETCH-neutral-or-better).
    const int b = blockIdx.x;
    const int xcd = b & 7;
    const int q = NBLK >> 3, rem = NBLK & 7;   // 118, 2
    const int wg = (xcd < rem ? xcd * (q + 1)
                              : rem * (q + 1) + (xcd - rem) * q) + (b >> 3);

    // Decode work id -> (ti, tj) with ti <= tj over TG=43.
    int r = wg, ti = 0;
    while (r >= TG - ti) { r -= TG - ti; ++ti; }
    const int tj = ti + r;

    const int tid = threadIdx.x;
    const int lane = tid & 63;
    const int w = tid >> 6;            // wave 0..3
    const int wr = w >> 1, wc = w & 1; // 2x2 wave grid, 48x48 region each
    const int rowBase = ti * 96, colBase = tj * 96;

    f32x4 acc[3][3];
#pragma unroll
    for (int mi = 0; mi < 3; ++mi)
#pragma unroll
        for (int ni = 0; ni < 3; ++ni) acc[mi][ni] = (f32x4){0.f, 0.f, 0.f, 0.f};

    // B staging: wave w stages chunks c = w*3 .. w*3+2 (12 total: 6rg x hi/lo).
    const f16* gB[3];
    f16* lpB[3];
#pragma unroll
    for (int j = 0; j < 3; ++j) {
        int c = w * 3 + j;
        int rgL = c >> 1, hl = c & 1;
        int rgG = tj * 6 + rgL;
        gB[j] = Xsw + ((((size_t)rgG * KC_COUNT) * 2 + hl) * 64 + lane) * 8;  // kc=0
        lpB[j] = Bs[0] + (rgL * 2 + hl) * 512;  // wave-uniform base (buf 0)
    }

    // A direct-load pointers: wave reads rows rgA = ti*6 + wr*3 + t2, hi/lo.
    const f16* gA[3][2];
#pragma unroll
    for (int t2 = 0; t2 < 3; ++t2) {
        int rgG = ti * 6 + wr * 3 + t2;
#pragma unroll
        for (int hl = 0; hl < 2; ++hl)
            gA[t2][hl] = Xsw + ((((size_t)rgG * KC_COUNT) * 2 + hl) * 64 + lane) * 8;
    }

    // Prologue: stage kc=0 into buf 0 (drains at the kc=0 barrier).
#pragma unroll
    for (int j = 0; j < 3; ++j)
        async_copy16(gB[j], lpB[j]);

    for (int kc = 0; kc < KC_COUNT; ++kc) {
        const size_t ko = (size_t)kc * 1024;
        const int cur = kc & 1;

        // A fragments for this step (plain global loads; compiler inserts
        // the vmcnt wait before first MFMA use).
        f16x8 ah[3], al[3];
#pragma unroll
        for (int t2 = 0; t2 < 3; ++t2) {
            ah[t2] = *(const f16x8*)(gA[t2][0] + ko);
            al[t2] = *(const f16x8*)(gA[t2][1] + ko);
        }

        __syncthreads();   // drains stage(kc); confirms buf^1 readers done

        // Stage next tile into the other buffer: in flight across this
        // step's ds_read + 27 MFMAs + next step's A-loads.
        if (kc + 1 < KC_COUNT) {
#pragma unroll
            for (int j = 0; j < 3; ++j)
                async_copy16(gB[j] + ko + 1024, lpB[j] + (cur ^ 1) * BUFSZ);
        }

        f16x8 bh[3], bl[3];
#pragma unroll
        for (int t2 = 0; t2 < 3; ++t2) {
            int rgB = wc * 3 + t2;
            bh[t2] = *(const f16x8*)(Bs[cur] + (rgB * 2 + 0) * 512 + lane * 8);
            bl[t2] = *(const f16x8*)(Bs[cur] + (rgB * 2 + 1) * 512 + lane * 8);
        }
#pragma unroll
        for (int mi = 0; mi < 3; ++mi)
#pragma unroll
            for (int ni = 0; ni < 3; ++ni) {
                acc[mi][ni] = __builtin_amdgcn_mfma_f32_16x16x32_f16(
                    ah[mi], bh[ni], acc[mi][ni], 0, 0, 0);
                acc[mi][ni] = __builtin_amdgcn_mfma_f32_16x16x32_f16(
                    ah[mi], bl[ni], acc[mi][ni], 0, 0, 0);
                acc[mi][ni] = __builtin_amdgcn_mfma_f32_16x16x32_f16(
                    al[mi], bh[ni], acc[mi][ni], 0, 0, 0);
            }
    }

    // Epilogue. C/D layout (16x16): col = lane&15, row = (lane>>4)*4 + reg.
    const int g16 = lane >> 4, c16 = lane & 15;

    int ljv[3], liv[3][4];
#pragma unroll
    for (int ni = 0; ni < 3; ++ni) {
        const int j = colBase + wc * 48 + ni * 16 + c16;
        ljv[ni] = (j < N) ? labels[j] : -1;    // pad sentinel: matches nothing
    }
#pragma unroll
    for (int mi = 0; mi < 3; ++mi)
#pragma unroll
        for (int reg = 0; reg < 4; ++reg) {
            const int i = rowBase + wr * 48 + mi * 16 + g16 * 4 + reg;
            liv[mi][reg] = (i < N) ? labels[i] : -1;
        }

    // Pass 1: row-side argmin (rows of ti-range over cols of tj-range).
#pragma unroll
    for (int mi = 0; mi < 3; ++mi) {
#pragma unroll
        for (int reg = 0; reg < 4; ++reg) {
            const int i = rowBase + wr * 48 + mi * 16 + g16 * 4 + reg;
            const int li = liv[mi][reg];
            float bestAp = __builtin_huge_valf(); int jAp = 0;
            float bestAn = __builtin_huge_valf(); int jAn = 0;
#pragma unroll
            for (int ni = 0; ni < 3; ++ni) {
                const int jcol = colBase + wc * 48 + ni * 16 + c16;
                const float v = acc[mi][ni][reg];
                const bool same = (li == ljv[ni]);
                const float vap = (same && (i != jcol)) ? v : v + 2.0f;
                const float van = (!same) ? v : v + 2.0f;
                if (vap < bestAp) { bestAp = vap; jAp = jcol; }
                if (van < bestAn) { bestAn = van; jAn = jcol; }
            }
            unsigned long long kap =
                ((unsigned long long)orderable(bestAp) << 32) | (unsigned)jAp;
            unsigned long long kan =
                ((unsigned long long)orderable(bestAn) << 32) | (unsigned)jAn;
#pragma unroll
            for (int off = 1; off < 16; off <<= 1) {
                unsigned long long o = __shfl_xor(kap, off); kap = o < kap ? o : kap;
                o = __shfl_xor(kan, off); kan = o < kan ? o : kan;
            }
            if (c16 == 0 && i < N) {
                atomicMin(&keys_ap[i], kap);
                atomicMin(&keys_an[i], kan);
            }
        }
    }

    // Pass 2 (off-diagonal only): column-side argmin via symmetry.
    if (ti != tj) {
#pragma unroll
        for (int ni = 0; ni < 3; ++ni) {
            const int j = colBase + wc * 48 + ni * 16 + c16;
            const int lj = ljv[ni];
            float bestAp = __builtin_huge_valf(); int iAp = 0;
            float bestAn = __builtin_huge_valf(); int iAn = 0;
#pragma unroll
            for (int mi = 0; mi < 3; ++mi)
#pragma unroll
                for (int reg = 0; reg < 4; ++reg) {
                    const int i = rowBase + wr * 48 + mi * 16 + g16 * 4 + reg;
                    const float v = acc[mi][ni][reg];
                    // pad rows have label -1 != lj -> negative, v = 0: never wins
                    const bool same = (liv[mi][reg] == lj);
                    const float vap = same ? v : v + 2.0f;   // i != j off-diag
                    const float van = (!same) ? v : v + 2.0f;
                    if (vap < bestAp) { bestAp = vap; iAp = i; }
                    if (van < bestAn) { bestAn = van; iAn = i; }
                }
            unsigned long long kap =
                ((unsigned long long)orderable(bestAp) << 32) | (unsigned)iAp;
            unsigned long long kan =
                ((unsigned long long)orderable(bestAn) << 32) | (unsigned)iAn;
            // Reduce over g16 (lane bits 4,5): lanes sharing c16 share j.
#pragma unroll
            for (int off = 16; off < 64; off <<= 1) {
                unsigned long long o = __shfl_xor(kap, off); kap = o < kap ? o : kap;
                o = __shfl_xor(kan, off); kan = o < kan ? o : kan;
            }
            if (g16 == 0 && j < N) {
                atomicMin(&keys_ap[j], kap);
                atomicMin(&keys_an[j], kan);
            }
        }
    }
}

__global__ void gather_rows(const float* __restrict__ A,
                            const unsigned long long* __restrict__ keys_ap,
                            const unsigned long long* __restrict__ keys_an,
                            float* __restrict__ out)
{
    const int row = blockIdx.x;
    const int t = threadIdx.x;
    const int ja = (int)(keys_ap[row] & 0xFFFFFFFFull);
    const int jn = (int)(keys_an[row] & 0xFFFFFFFFull);
    const float4* Av = (const float4*)A;
    float4* Ov = (float4*)out;
    Ov[(size_t)row * (D / 4) + t]       = Av[(size_t)ja * (D / 4) + t];
    Ov[(size_t)(N + row) * (D / 4) + t] = Av[(size_t)jn * (D / 4) + t];
}

extern "C" void kernel_launch(void* const* d_in, const int* in_sizes, int n_in,
                              void* d_out, int out_size, void* d_ws, size_t ws_size,
                              hipStream_t stream) {
    const float* A = (const float*)d_in[0];
    const int* labels = (const int*)d_in[1];  // integer inputs arrive as int32
    float* out = (float*)d_out;

    unsigned long long* keys = (unsigned long long*)d_ws;          // 64 KB
    f16* Xsw = (f16*)((char*)d_ws + 65536);   // 258 rg * 64 KB = 16.9 MB hi+lo

    split_direct<<<258 * 4, 256, 0, stream>>>(A, Xsw, keys);
    gemm_argmin_sym<<<NBLK, 256, 0, stream>>>(Xsw, labels, keys, keys + N);
    gather_rows<<<N, 256, 0, stream>>>(A, keys, keys + N, out);
}